// Round 8
// baseline (1792.094 us; speedup 1.0000x reference)
//
#include <hip/hip_runtime.h>
#include <hip/hip_bf16.h>
#include <stdint.h>

typedef __attribute__((ext_vector_type(8))) short short8;       // 8 bf16 (MFMA frag)
typedef __attribute__((ext_vector_type(4))) float f32x4;
typedef __attribute__((ext_vector_type(8))) unsigned short u16x8;

static __device__ __forceinline__ unsigned short f2bf(float f) {
  union { float f; unsigned int u; } c; c.f = f;
  unsigned int u = c.u;
  u += 0x7FFFu + ((u >> 16) & 1u);
  return (unsigned short)(u >> 16);
}
static __device__ __forceinline__ float bf2f(unsigned short h) {
  union { unsigned int u; float f; } c; c.u = ((unsigned int)h) << 16;
  return c.f;
}
static __device__ __forceinline__ f32x4 mfma_bf16(short8 a, short8 b, f32x4 c) {
  return __builtin_amdgcn_mfma_f32_16x16x32_bf16(a, b, c, 0, 0, 0);
}
static __device__ __forceinline__ void gl_lds16(const void* g, void* lds) {
  __builtin_amdgcn_global_load_lds(
      (const __attribute__((address_space(1))) void*)(unsigned long long)(uintptr_t)g,
      (__attribute__((address_space(3))) void*)(unsigned int)(uintptr_t)lds,
      16, 0, 0);
}

// ---------------------------------------------------------------------------
// convert kernels
// ---------------------------------------------------------------------------
__global__ void k_cvt_w(const float* __restrict__ w, const float* __restrict__ s,
                        unsigned short* __restrict__ o, int N, int K) {
  const int KB = K >> 7;
  const size_t total = ((size_t)N * K) >> 3;
  for (size_t i = (size_t)blockIdx.x * blockDim.x + threadIdx.x; i < total;
       i += (size_t)gridDim.x * blockDim.x) {
    const size_t e = i << 3;
    const int n = (int)(e / K);
    const int k = (int)(e % K);
    const float sc = s[(n >> 7) * KB + (k >> 7)];
    f32x4 a = *(const f32x4*)(w + e);
    f32x4 b = *(const f32x4*)(w + e + 4);
    u16x8 q;
    #pragma unroll
    for (int j = 0; j < 4; ++j) { q[j] = f2bf(a[j] * sc); q[4 + j] = f2bf(b[j] * sc); }
    *(u16x8*)(o + e) = q;
  }
}

__global__ void k_cvt_x(const float* __restrict__ x, unsigned short* __restrict__ o,
                        size_t total8) {
  for (size_t i = (size_t)blockIdx.x * blockDim.x + threadIdx.x; i < total8;
       i += (size_t)gridDim.x * blockDim.x) {
    const size_t e = i << 3;
    f32x4 a = *(const f32x4*)(x + e);
    f32x4 b = *(const f32x4*)(x + e + 4);
    u16x8 q;
    #pragma unroll
    for (int j = 0; j < 4; ++j) { q[j] = f2bf(a[j]); q[4 + j] = f2bf(b[j]); }
    *(u16x8*)(o + e) = q;
  }
}

// ---------------------------------------------------------------------------
// Derived-waits 8-phase GEMM (R8): reads(p) feed MFMA(p+1); MID waits
// lgkmcnt(K_p) = reads issued in p (drains older, keeps fresh in flight).
// vmcnt(6/4) at end-P2 only (3 half-tiles in flight); vmcnt(0) final pair.
// Frag slots ping-pong (aS0/aS1, bX/bY parity-swapped per tile); every
// LDS overwrite sits behind a barrier following its readers' lgkm-drain.
// EPI: 0 = bf16 store; 1 = silu(Gin)*acc -> bf16; 2 = f32 store.
// ---------------------------------------------------------------------------
#define SB  __builtin_amdgcn_sched_barrier(0)
#define BAR __builtin_amdgcn_s_barrier()
#define LGKM(n) asm volatile("s_waitcnt lgkmcnt(%0)" :: "n"(n) : "memory")
#define VMC(n)  asm volatile("s_waitcnt vmcnt(%0)"  :: "n"(n) : "memory")
#define MID(n) do { SB; BAR; LGKM(n); SB; __builtin_amdgcn_s_setprio(1); } while (0)
#define ENDP() do { __builtin_amdgcn_s_setprio(0); SB; BAR; } while (0)

#define RD_A(slot, mh, dst) do { \
    const char* _ba = (const char*)lds + ((slot) * 2 + wm) * 16384; \
    _Pragma("unroll") \
    for (int f = 0; f < 4; ++f) { \
      dst[0][f] = *(const short8*)(_ba + ((((mh) * 64 + f * 16 + lr) * 128 + kg * 16) ^ xr)); \
      dst[1][f] = *(const short8*)(_ba + ((((mh) * 64 + f * 16 + lr) * 128 + 64 + kg * 16) ^ xr)); \
    } } while (0)
#define RD_B(slot, nh, dst) do { \
    const char* _bb = (const char*)lds + ABYTES + ((slot) * NBH + bhalf) * 16384; \
    _Pragma("unroll") \
    for (int f = 0; f < NH2; ++f) { \
      dst[0][f] = *(const short8*)(_bb + (((wrow0 + ((nh) * NH2 + f) * 16 + lr) * 128 + kg * 16) ^ xr)); \
      dst[1][f] = *(const short8*)(_bb + (((wrow0 + ((nh) * NH2 + f) * 16 + lr) * 128 + 64 + kg * 16) ^ xr)); \
    } } while (0)
#define MF(aS, bS, mh, nh) do { \
    _Pragma("unroll") \
    for (int m = 0; m < 4; ++m) \
      _Pragma("unroll") \
      for (int n = 0; n < NH2; ++n) { \
        acc[(mh)*4+m][(nh)*NH2+n] = mfma_bf16(aS[0][m], bS[0][n], acc[(mh)*4+m][(nh)*NH2+n]); \
        acc[(mh)*4+m][(nh)*NH2+n] = mfma_bf16(aS[1][m], bS[1][n], acc[(mh)*4+m][(nh)*NH2+n]); \
      } } while (0)

template<int NB, int EPI>
__global__ __launch_bounds__(512, 2)
void k_gemm8p(const unsigned short* __restrict__ A,
              const unsigned short* __restrict__ B,
              const unsigned short* Gin,
              void* Out,
              int M, int N, int K) {
  constexpr int BN     = NB * 128;
  constexpr int NREP   = NB * 2;
  constexpr int NH2    = NREP / 2;
  constexpr int NBH    = NB;
  constexpr int ABYTES = 65536;
  constexpr int LG0    = 2 * NH2;        // P0 lookahead reads (B1)
  constexpr int LG1    = 8;              // P1 lookahead reads (A1)
  constexpr int LG3    = 8 + 2 * NH2;    // P3 lookahead reads (A0',B0')
  constexpr int VMN    = (NB == 2) ? 6 : 4;   // stages since tile t+1 landed
  constexpr int VPR    = (NB == 2) ? 8 : 6;   // prologue: tile-1 stages
  __shared__ unsigned short lds[(NB == 2) ? 65536 : 49152];

  const int tid  = threadIdx.x;
  const int lane = tid & 63;
  const int wid  = tid >> 6;
  const int wm   = wid >> 2;
  const int wn   = wid & 3;
  const int lr   = lane & 15;
  const int kg   = lane >> 4;
  const int xr   = (lr & 7) << 4;

  const int nwg = gridDim.x;
  const int per = nwg >> 3;
  const int wg  = (int)blockIdx.x;
  const int swz = (wg & 7) * per + (wg >> 3);
  const int bm  = swz & 7;
  const int bn  = swz >> 3;

  const int r0   = tid >> 3;
  const int colb = ((tid & 7) ^ ((tid >> 3) & 7)) << 4;
  const size_t ldb = (size_t)K * 2;

  const char* gA = (const char*)A + (size_t)bm * 256 * ldb;
  const char* gB = (const char*)B + (size_t)bn * BN * ldb;

  const int wrow0 = (NB == 2) ? (wn & 1) * 64 : wn * 32;
  const int bhalf = (NB == 2) ? (wn >> 1) : 0;

  auto stageA = [&](int t, int h) {
    unsigned short* d = lds + ((t & 1) * 2 + h) * 8192 + wid * 512;
    const char* s = gA + (size_t)(h * 128 + r0) * ldb + (size_t)t * 128 + colb;
    gl_lds16(s, d);
    gl_lds16(s + 64 * ldb, d + 4096);
  };
  auto stageB = [&](int t, int h) {
    unsigned short* d = lds + (ABYTES / 2) + ((t & 1) * NBH + h) * 8192 + wid * 512;
    const char* s = gB + (size_t)(h * 128 + r0) * ldb + (size_t)t * 128 + colb;
    gl_lds16(s, d);
    gl_lds16(s + 64 * ldb, d + 4096);
  };

  f32x4 acc[8][NREP];
  #pragma unroll
  for (int m = 0; m < 8; ++m)
    #pragma unroll
    for (int n = 0; n < NREP; ++n)
      #pragma unroll
      for (int e = 0; e < 4; ++e) acc[m][n][e] = 0.0f;

  short8 aS0[2][4], aS1[2][4], bX[2][NH2], bY[2][NH2];

  const int NT = K >> 6;
  const int NP = NT >> 1;

  // prologue: stage tiles 0,1; tile-0-ready barrier; lookahead reads for P0
  stageA(0, 0); stageA(0, 1); stageB(0, 0); if constexpr (NB == 2) stageB(0, 1);
  stageA(1, 0); stageA(1, 1); stageB(1, 0); if constexpr (NB == 2) stageB(1, 1);
  VMC(VPR); SB; BAR;
  RD_A(0, 0, aS0);            // A0(t0)
  RD_B(0, 0, bX);             // B0(t0)  (even tile: B0->bX, B1->bY)

  for (int i = 0; i < NP; ++i) {
    const int t0 = 2 * i;
    const bool more = (i + 1 < NP);

    // ================= tile t0 (even, slot0; p=bX, q=bY) =================
    // P0: read B1(t0)->bY
    RD_B(0, 1, bY);
    MID(LG0); MF(aS0, bX, 0, 0); ENDP();
    // P1: read A1(t0)->aS1 ; stage A(t0+2,h0), B(t0+2,h0)
    RD_A(0, 1, aS1);
    if (more) { stageA(t0 + 2, 0); stageB(t0 + 2, 0); }
    MID(LG1); MF(aS0, bY, 0, 1); ENDP();
    // P2: stage B(t0+2,h1) ; end-wait licenses tile t1's reads at P3
    if (more) { if constexpr (NB == 2) stageB(t0 + 2, 1); }
    MID(0); MF(aS1, bY, 1, 1);
    __builtin_amdgcn_s_setprio(0); SB;
    if (more) { VMC(VMN); } else { VMC(0); }
    SB; BAR;
    // P3: lookahead reads tile t1 (odd: B0->bY) ; stage A(t0+2,h1)
    RD_A(1, 0, aS0);
    RD_B(1, 0, bY);
    if (more) stageA(t0 + 2, 1);
    MID(LG3); MF(aS1, bX, 1, 0); ENDP();

    // ================= tile t1 (odd, slot1; p=bY, q=bX) =================
    // P0: read B1(t1)->bX
    RD_B(1, 1, bX);
    MID(LG0); MF(aS0, bY, 0, 0); ENDP();
    // P1: read A1(t1)->aS1 ; stage A(t1+2,h0), B(t1+2,h0)
    RD_A(1, 1, aS1);
    if (more) { stageA(t0 + 3, 0); stageB(t0 + 3, 0); }
    MID(LG1); MF(aS0, bX, 0, 1); ENDP();
    // P2: stage B(t1+2,h1) ; end-wait licenses tile t0+2's reads at P3
    if (more) { if constexpr (NB == 2) stageB(t0 + 3, 1); }
    MID(0); MF(aS1, bX, 1, 1);
    __builtin_amdgcn_s_setprio(0); SB;
    if (more) { VMC(VMN); } else { VMC(0); }
    SB; BAR;
    // P3: lookahead reads tile t0+2 (even: B0->bX) ; stage A(t1+2,h1)
    if (more) {
      RD_A(0, 0, aS0);
      RD_B(0, 0, bX);
      stageA(t0 + 3, 1);
      MID(LG3);
    } else {
      MID(0);
    }
    MF(aS1, bY, 1, 0); ENDP();
  }

  // epilogue: C/D map col=lane&15, row=(lane>>4)*4+j  [m89-verified, R1-R7]
  const int growb = bm * 256 + wm * 128 + kg * 4;
  const int gcolb = bn * BN + wn * (BN / 4) + lr;
  #pragma unroll
  for (int m = 0; m < 8; ++m)
    #pragma unroll
    for (int n = 0; n < NREP; ++n)
      #pragma unroll
      for (int j = 0; j < 4; ++j) {
        const size_t idx = (size_t)(growb + m * 16 + j) * N + (gcolb + n * 16);
        if constexpr (EPI == 0) {
          ((unsigned short*)Out)[idx] = f2bf(acc[m][n][j]);
        } else if constexpr (EPI == 1) {
          const float gv = bf2f(Gin[idx]);
          const float sg = gv / (1.0f + __expf(-gv));
          ((unsigned short*)Out)[idx] = f2bf(sg * acc[m][n][j]);
        } else {
          ((float*)Out)[idx] = acc[m][n][j];
        }
      }
}

extern "C" void kernel_launch(void* const* d_in, const int* in_sizes, int n_in,
                              void* d_out, int out_size, void* d_ws, size_t ws_size,
                              hipStream_t stream) {
  const float* x   = (const float*)d_in[0];
  const float* w1  = (const float*)d_in[1];
  const float* w1s = (const float*)d_in[2];
  const float* w3  = (const float*)d_in[3];
  const float* w3s = (const float*)d_in[4];
  const float* w2  = (const float*)d_in[5];
  const float* w2s = (const float*)d_in[6];
  float* y = (float*)d_out;

  const int D = 4096, I = 14336;
  const int T = in_sizes[0] / D;          // 2048

  const size_t xbB = (size_t)T * D * 2;
  const size_t wB  = (size_t)I * D * 2;

  char* ws = (char*)d_ws;
  unsigned short* xb  = (unsigned short*)(ws);
  unsigned short* w1b = (unsigned short*)(ws + xbB);
  unsigned short* w3b = (unsigned short*)(ws + xbB + wB);
  unsigned short* w2b = (unsigned short*)(ws + xbB + 2 * wB);
  unsigned short* g   = (unsigned short*)(ws + xbB + 3 * wB);   // g -> h in place

  k_cvt_x<<<2048, 256, 0, stream>>>(x, xb, ((size_t)T * D) >> 3);
  k_cvt_w<<<2048, 256, 0, stream>>>(w1, w1s, w1b, I, D);
  k_cvt_w<<<2048, 256, 0, stream>>>(w3, w3s, w3b, I, D);
  k_cvt_w<<<2048, 256, 0, stream>>>(w2, w2s, w2b, D, I);

  // gate: g = xb @ w1b^T           grid 8*56 = 448
  k_gemm8p<2, 0><<<dim3((T / 256) * (I / 256)), dim3(512), 0, stream>>>(
      xb, w1b, nullptr, g, T, I, D);
  // up:   h = silu(g) * (xb @ w3b^T), in-place over g
  k_gemm8p<2, 1><<<dim3((T / 256) * (I / 256)), dim3(512), 0, stream>>>(
      xb, w3b, g, g, T, I, D);
  // down: y = h @ w2b^T            grid 8*32 = 256 (BN=128)
  k_gemm8p<1, 2><<<dim3((T / 256) * (D / 128)), dim3(512), 0, stream>>>(
      g, w2b, nullptr, y, T, D, I);
}

// Round 9
// 856.802 us; speedup vs baseline: 2.0916x; 2.0916x over previous
//
#include <hip/hip_runtime.h>
#include <hip/hip_bf16.h>
#include <stdint.h>

typedef __attribute__((ext_vector_type(8))) short short8;       // 8 bf16 (MFMA frag)
typedef __attribute__((ext_vector_type(4))) float f32x4;
typedef __attribute__((ext_vector_type(8))) unsigned short u16x8;

static __device__ __forceinline__ unsigned short f2bf(float f) {
  union { float f; unsigned int u; } c; c.f = f;
  unsigned int u = c.u;
  u += 0x7FFFu + ((u >> 16) & 1u);
  return (unsigned short)(u >> 16);
}
static __device__ __forceinline__ f32x4 mfma_bf16(short8 a, short8 b, f32x4 c) {
  return __builtin_amdgcn_mfma_f32_16x16x32_bf16(a, b, c, 0, 0, 0);
}
static __device__ __forceinline__ void gl_lds16(const void* g, void* lds) {
  __builtin_amdgcn_global_load_lds(
      (const __attribute__((address_space(1))) void*)(unsigned long long)(uintptr_t)g,
      (__attribute__((address_space(3))) void*)(unsigned int)(uintptr_t)lds,
      16, 0, 0);
}

// ---------------------------------------------------------------------------
// convert kernels
// ---------------------------------------------------------------------------
__global__ void k_cvt_w(const float* __restrict__ w, const float* __restrict__ s,
                        unsigned short* __restrict__ o, int N, int K) {
  const int KB = K >> 7;
  const size_t total = ((size_t)N * K) >> 3;
  for (size_t i = (size_t)blockIdx.x * blockDim.x + threadIdx.x; i < total;
       i += (size_t)gridDim.x * blockDim.x) {
    const size_t e = i << 3;
    const int n = (int)(e / K);
    const int k = (int)(e % K);
    const float sc = s[(n >> 7) * KB + (k >> 7)];
    f32x4 a = *(const f32x4*)(w + e);
    f32x4 b = *(const f32x4*)(w + e + 4);
    u16x8 q;
    #pragma unroll
    for (int j = 0; j < 4; ++j) { q[j] = f2bf(a[j] * sc); q[4 + j] = f2bf(b[j] * sc); }
    *(u16x8*)(o + e) = q;
  }
}

__global__ void k_cvt_x(const float* __restrict__ x, unsigned short* __restrict__ o,
                        size_t total8) {
  for (size_t i = (size_t)blockIdx.x * blockDim.x + threadIdx.x; i < total8;
       i += (size_t)gridDim.x * blockDim.x) {
    const size_t e = i << 3;
    f32x4 a = *(const f32x4*)(x + e);
    f32x4 b = *(const f32x4*)(x + e + 4);
    u16x8 q;
    #pragma unroll
    for (int j = 0; j < 4; ++j) { q[j] = f2bf(a[j]); q[4 + j] = f2bf(b[j]); }
    *(u16x8*)(o + e) = q;
  }
}

// ---------------------------------------------------------------------------
// Fused gate+up GEMM + SwiGLU (R5 loop structure, proven):
//   h = silu(xb @ w1b^T) * (xb @ w3b^T)  -> bf16 [M][N]
// BM=256, BN=128, BK=64; 512 thr = 8 waves (2Mx4N); per-wave 128x32 out x2.
// LDS 128KB: A dbuf 64KB (slots (2t+h)&3), B1 32KB + B3 32KB (slots t&1).
// Per K-tile: 12 ds_read_b128-x8 frags -> 64 MFMA (2x R5 density).
// vmcnt(8) top-of-loop (stage=8 loads/tile, 2 tiles in flight), lgkm(0)
// +barrier before stage(t+2) overwrite. Swizzle: pre-swizzled global src +
// XOR on ds_read (R5-proven, 0 conflicts).
// ---------------------------------------------------------------------------
__global__ __launch_bounds__(512, 2)
void k_gateup_f(const unsigned short* __restrict__ A,
                const unsigned short* __restrict__ B1,
                const unsigned short* __restrict__ B3,
                unsigned short* __restrict__ H,
                int N, int K) {
  __shared__ unsigned short lds[65536];   // 128KB

  const int tid  = threadIdx.x;
  const int lane = tid & 63;
  const int wid  = tid >> 6;
  const int wm   = wid >> 2;              // 0..1
  const int wn   = wid & 3;               // 0..3
  const int lr   = lane & 15;
  const int kg   = lane >> 4;
  const int xr   = (lr & 7) << 4;

  const int nwg = gridDim.x;              // 896, %8==0
  const int per = nwg >> 3;
  const int wg  = (int)blockIdx.x;
  const int swz = (wg & 7) * per + (wg >> 3);
  const int bm  = swz & 7;                // M/256 = 8, fastest
  const int bn  = swz >> 3;               // 0..111

  const int r0   = tid >> 3;
  const int colb = ((tid & 7) ^ ((tid >> 3) & 7)) << 4;
  const size_t ldb = (size_t)K * 2;

  const char* gA = (const char*)A  + (size_t)bm * 256 * ldb;
  const char* g1 = (const char*)B1 + (size_t)bn * 128 * ldb;
  const char* g3 = (const char*)B3 + (size_t)bn * 128 * ldb;

  auto stage = [&](int t) {
    const size_t kb = (size_t)t * 128;
    #pragma unroll
    for (int h = 0; h < 2; ++h) {          // A: 256 rows, 4 loads
      unsigned short* d = lds + (((2 * t + h) & 3) * 8192) + wid * 512;
      const char* s = gA + (size_t)(h * 128 + r0) * ldb + kb + colb;
      gl_lds16(s,            d);
      gl_lds16(s + 64 * ldb, d + 4096);
    }
    {                                      // B1: 128 rows, 2 loads
      unsigned short* d = lds + 32768 + ((t & 1) * 8192) + wid * 512;
      const char* s = g1 + (size_t)r0 * ldb + kb + colb;
      gl_lds16(s,            d);
      gl_lds16(s + 64 * ldb, d + 4096);
    }
    {                                      // B3: 128 rows, 2 loads
      unsigned short* d = lds + 49152 + ((t & 1) * 8192) + wid * 512;
      const char* s = g3 + (size_t)r0 * ldb + kb + colb;
      gl_lds16(s,            d);
      gl_lds16(s + 64 * ldb, d + 4096);
    }
  };

  f32x4 accg[8][2], accu[8][2];
  #pragma unroll
  for (int m = 0; m < 8; ++m)
    #pragma unroll
    for (int n = 0; n < 2; ++n)
      #pragma unroll
      for (int e = 0; e < 4; ++e) { accg[m][n][e] = 0.0f; accu[m][n][e] = 0.0f; }

  const int wrow0 = wn * 32;
  const int NT = K >> 6;

  stage(0);
  stage(1);

  for (int t = 0; t < NT; ++t) {
    if (t == NT - 1) asm volatile("s_waitcnt vmcnt(0)" ::: "memory");
    else             asm volatile("s_waitcnt vmcnt(8)" ::: "memory");
    __builtin_amdgcn_s_barrier();
    __builtin_amdgcn_sched_barrier(0);

    const char* ab  = (const char*)lds + (((2 * t + wm) & 3) * 16384);
    const char* b1b = (const char*)lds + 65536 + ((t & 1) * 16384);
    const char* b3b = (const char*)lds + 98304 + ((t & 1) * 16384);

    short8 a0[8], p0[2], q0[2], a1[8], p1[2], q1[2];
    #pragma unroll
    for (int m = 0; m < 8; ++m)
      a0[m] = *(const short8*)(ab + ((((m * 16 + lr) * 128) + kg * 16) ^ xr));
    #pragma unroll
    for (int n = 0; n < 2; ++n) {
      p0[n] = *(const short8*)(b1b + ((((wrow0 + n * 16 + lr) * 128) + kg * 16) ^ xr));
      q0[n] = *(const short8*)(b3b + ((((wrow0 + n * 16 + lr) * 128) + kg * 16) ^ xr));
    }
    #pragma unroll
    for (int m = 0; m < 8; ++m)
      #pragma unroll
      for (int n = 0; n < 2; ++n) {
        accg[m][n] = mfma_bf16(a0[m], p0[n], accg[m][n]);
        accu[m][n] = mfma_bf16(a0[m], q0[n], accu[m][n]);
      }

    #pragma unroll
    for (int m = 0; m < 8; ++m)
      a1[m] = *(const short8*)(ab + ((((m * 16 + lr) * 128) + 64 + kg * 16) ^ xr));
    #pragma unroll
    for (int n = 0; n < 2; ++n) {
      p1[n] = *(const short8*)(b1b + ((((wrow0 + n * 16 + lr) * 128) + 64 + kg * 16) ^ xr));
      q1[n] = *(const short8*)(b3b + ((((wrow0 + n * 16 + lr) * 128) + 64 + kg * 16) ^ xr));
    }

    asm volatile("s_waitcnt lgkmcnt(0)" ::: "memory");
    __builtin_amdgcn_s_barrier();
    __builtin_amdgcn_sched_barrier(0);
    if (t + 2 < NT) stage(t + 2);
    __builtin_amdgcn_sched_barrier(0);

    #pragma unroll
    for (int m = 0; m < 8; ++m)
      #pragma unroll
      for (int n = 0; n < 2; ++n) {
        accg[m][n] = mfma_bf16(a1[m], p1[n], accg[m][n]);
        accu[m][n] = mfma_bf16(a1[m], q1[n], accu[m][n]);
      }
  }

  // epilogue: silu(g)*u -> bf16; C/D map col=lane&15, row=(lane>>4)*4+j
  const int growb = bm * 256 + wm * 128 + kg * 4;
  const int gcolb = bn * 128 + wn * 32 + lr;
  #pragma unroll
  for (int m = 0; m < 8; ++m)
    #pragma unroll
    for (int n = 0; n < 2; ++n)
      #pragma unroll
      for (int j = 0; j < 4; ++j) {
        const float g  = accg[m][n][j];
        const float u  = accu[m][n][j];
        const float sg = g / (1.0f + __expf(-g));
        H[(size_t)(growb + m * 16 + j) * N + (gcolb + n * 16)] = f2bf(sg * u);
      }
}

// ---------------------------------------------------------------------------
// Down GEMM (R5 NB1 structure, LDS ring fixed in-bounds at 128KB):
//   y = h @ w2b^T, f32 out. BM=256, BN=128.
// ---------------------------------------------------------------------------
__global__ __launch_bounds__(512, 2)
void k_down256(const unsigned short* __restrict__ A,
               const unsigned short* __restrict__ B,
               float* __restrict__ Y,
               int N, int K) {
  __shared__ unsigned short lds[65536];   // 128KB (A ring 64KB + B ring 64KB)

  const int tid  = threadIdx.x;
  const int lane = tid & 63;
  const int wid  = tid >> 6;
  const int wm   = wid >> 2;
  const int wn   = wid & 3;
  const int lr   = lane & 15;
  const int kg   = lane >> 4;
  const int xr   = (lr & 7) << 4;

  const int nwg = gridDim.x;              // 256
  const int per = nwg >> 3;
  const int wg  = (int)blockIdx.x;
  const int swz = (wg & 7) * per + (wg >> 3);
  const int bm  = swz & 7;
  const int bn  = swz >> 3;

  const int r0   = tid >> 3;
  const int colb = ((tid & 7) ^ ((tid >> 3) & 7)) << 4;
  const size_t ldb = (size_t)K * 2;

  const char* gA = (const char*)A + (size_t)bm * 256 * ldb;
  const char* gB = (const char*)B + (size_t)bn * 128 * ldb;

  auto stage = [&](int t) {
    const size_t kb = (size_t)t * 128;
    #pragma unroll
    for (int h = 0; h < 2; ++h) {
      unsigned short* d = lds + (((2 * t + h) & 3) * 8192) + wid * 512;
      const char* s = gA + (size_t)(h * 128 + r0) * ldb + kb + colb;
      gl_lds16(s,            d);
      gl_lds16(s + 64 * ldb, d + 4096);
    }
    {
      unsigned short* d = lds + 32768 + ((t & 3) * 8192) + wid * 512;
      const char* s = gB + (size_t)r0 * ldb + kb + colb;
      gl_lds16(s,            d);
      gl_lds16(s + 64 * ldb, d + 4096);
    }
  };

  f32x4 acc[8][2];
  #pragma unroll
  for (int m = 0; m < 8; ++m)
    #pragma unroll
    for (int n = 0; n < 2; ++n)
      #pragma unroll
      for (int e = 0; e < 4; ++e) acc[m][n][e] = 0.0f;

  const int wrow0 = wn * 32;
  const int NT = K >> 6;

  stage(0);
  stage(1);

  for (int t = 0; t < NT; ++t) {
    if (t == NT - 1) asm volatile("s_waitcnt vmcnt(0)" ::: "memory");
    else             asm volatile("s_waitcnt vmcnt(6)" ::: "memory");
    __builtin_amdgcn_s_barrier();
    __builtin_amdgcn_sched_barrier(0);

    const char* ab = (const char*)lds + (((2 * t + wm) & 3) * 16384);
    const char* bb = (const char*)lds + 65536 + ((t & 3) * 16384);

    short8 a0[8], b0[2], a1[8], b1[2];
    #pragma unroll
    for (int m = 0; m < 8; ++m)
      a0[m] = *(const short8*)(ab + ((((m * 16 + lr) * 128) + kg * 16) ^ xr));
    #pragma unroll
    for (int n = 0; n < 2; ++n)
      b0[n] = *(const short8*)(bb + ((((wrow0 + n * 16 + lr) * 128) + kg * 16) ^ xr));
    #pragma unroll
    for (int m = 0; m < 8; ++m)
      #pragma unroll
      for (int n = 0; n < 2; ++n)
        acc[m][n] = mfma_bf16(a0[m], b0[n], acc[m][n]);

    #pragma unroll
    for (int m = 0; m < 8; ++m)
      a1[m] = *(const short8*)(ab + ((((m * 16 + lr) * 128) + 64 + kg * 16) ^ xr));
    #pragma unroll
    for (int n = 0; n < 2; ++n)
      b1[n] = *(const short8*)(bb + ((((wrow0 + n * 16 + lr) * 128) + 64 + kg * 16) ^ xr));

    asm volatile("s_waitcnt lgkmcnt(0)" ::: "memory");
    __builtin_amdgcn_s_barrier();
    __builtin_amdgcn_sched_barrier(0);
    if (t + 2 < NT) stage(t + 2);
    __builtin_amdgcn_sched_barrier(0);

    #pragma unroll
    for (int m = 0; m < 8; ++m)
      #pragma unroll
      for (int n = 0; n < 2; ++n)
        acc[m][n] = mfma_bf16(a1[m], b1[n], acc[m][n]);
  }

  const int growb = bm * 256 + wm * 128 + kg * 4;
  const int gcolb = bn * 128 + wn * 32 + lr;
  #pragma unroll
  for (int m = 0; m < 8; ++m)
    #pragma unroll
    for (int n = 0; n < 2; ++n)
      #pragma unroll
      for (int j = 0; j < 4; ++j)
        Y[(size_t)(growb + m * 16 + j) * N + (gcolb + n * 16)] = acc[m][n][j];
}

extern "C" void kernel_launch(void* const* d_in, const int* in_sizes, int n_in,
                              void* d_out, int out_size, void* d_ws, size_t ws_size,
                              hipStream_t stream) {
  const float* x   = (const float*)d_in[0];
  const float* w1  = (const float*)d_in[1];
  const float* w1s = (const float*)d_in[2];
  const float* w3  = (const float*)d_in[3];
  const float* w3s = (const float*)d_in[4];
  const float* w2  = (const float*)d_in[5];
  const float* w2s = (const float*)d_in[6];
  float* y = (float*)d_out;

  const int D = 4096, I = 14336;
  const int T = in_sizes[0] / D;          // 2048

  const size_t xbB = (size_t)T * D * 2;
  const size_t wB  = (size_t)I * D * 2;

  char* ws = (char*)d_ws;
  unsigned short* xb  = (unsigned short*)(ws);
  unsigned short* w1b = (unsigned short*)(ws + xbB);
  unsigned short* w3b = (unsigned short*)(ws + xbB + wB);
  unsigned short* w2b = (unsigned short*)(ws + xbB + 2 * wB);
  unsigned short* h   = (unsigned short*)(ws + xbB + 3 * wB);

  k_cvt_x<<<2048, 256, 0, stream>>>(x, xb, ((size_t)T * D) >> 3);
  k_cvt_w<<<2048, 256, 0, stream>>>(w1, w1s, w1b, I, D);
  k_cvt_w<<<2048, 256, 0, stream>>>(w3, w3s, w3b, I, D);
  k_cvt_w<<<2048, 256, 0, stream>>>(w2, w2s, w2b, D, I);

  // fused gate+up+SwiGLU: h = silu(xb@w1b^T) * (xb@w3b^T)   grid 8*112 = 896
  k_gateup_f<<<dim3((T / 256) * (I / 128)), dim3(512), 0, stream>>>(
      xb, w1b, w3b, h, I, D);
  // down: y = h @ w2b^T                                     grid 8*32 = 256
  k_down256<<<dim3((T / 256) * (D / 128)), dim3(512), 0, stream>>>(
      h, w2b, y, D, I);
}